// Round 5
// baseline (157.531 us; speedup 1.0000x reference)
//
#include <hip/hip_runtime.h>
#include <hip/hip_bf16.h>

// Problem sizes (fixed by the reference)
#define LROWS 8192
#define BROWS 4096
#define DDIM  1024

typedef __attribute__((ext_vector_type(4)))  int   i32x4;
typedef __attribute__((ext_vector_type(8)))  int   i32x8;
typedef __attribute__((ext_vector_type(16))) float f32x16;

// address-space-qualified pointer typedefs for global_load_lds
typedef const unsigned int __attribute__((address_space(1))) gu32;
typedef unsigned int       __attribute__((address_space(3))) su32;

// pack 4 floats -> 4 fp8 e4m3 bytes (OCP e4m3fn on gfx950)
__device__ inline unsigned int pack_fp8x4(float4 v) {
    unsigned int w = 0;
    w = __builtin_amdgcn_cvt_pk_fp8_f32(v.x, v.y, w, false);  // bytes 0,1
    w = __builtin_amdgcn_cvt_pk_fp8_f32(v.z, v.w, w, true);   // bytes 2,3
    return w;
}

// ---------------- prep: fp32->fp8 cast + pos diag dots ONLY (unchanged from R8) ----------------
__global__ __launch_bounds__(256) void prep_kernel(
    const float4* __restrict__ pred,
    const float4* __restrict__ gt,
    unsigned int* __restrict__ opred,   // fp8, 256 uints per row
    unsigned int* __restrict__ ogt,
    float* __restrict__ pos,
    float* __restrict__ out) {
    __shared__ float sred[4];
    const int row = blockIdx.x;
    const int t = threadIdx.x;
    if (row == 0 && t == 0) out[0] = 0.0f;

    const int idx = row * 256 + t;
    float4 p = pred[idx];
    float4 g = gt[idx];
    opred[idx] = pack_fp8x4(p);
    ogt[idx]   = pack_fp8x4(g);
    float s = p.x * g.x + p.y * g.y + p.z * g.z + p.w * g.w;

    #pragma unroll
    for (int o = 32; o > 0; o >>= 1) s += __shfl_down(s, o, 64);
    if ((t & 63) == 0) sred[t >> 6] = s;
    __syncthreads();
    if (t == 0) pos[row] = sred[0] + sred[1] + sred[2] + sred[3];
}

// ---------------- hinge GEMM v6 (MX fp8): 128x128 tile, 2 waves, 4 blocks/CU ----------------
// R11: R9/R10 scheduling edits at the 256²/1-block-per-CU geometry were both NULL — the
// stall is structural lockstep: with one block per CU and a barrier per K-step, all waves
// ds_read together (LDS pipe ~2300 cyc, matrix idle) then MFMA together (~2200 cyc, LDS
// idle); near-parity pipes ADD. The only session config that overlapped them was R5's:
// independent blocks per CU antiphasing across barriers (m114 mechanism, 1040 TF at
// 4 blocks/CU despite full __syncthreads drains). R7's win over R5 was arithmetic
// intensity (1.5 KB LDS per mfma vs 2 KB), which is tile-shape-independent.
// v6 combines both: 128x128 block tile, TWO waves (wave tile 128x64 = 4x2 of
// mfma_scale_32x32x64 -> 1.5 KB/mfma kept), BK=128 single-buffered (32 KB LDS),
// grid 1024 -> 4 blocks/CU (all 1024 resident), R5's plain 2-barrier-per-tile sync.
// Cross-block antiphase hides both the stage drain AND serializes the pipes' usage.
// Same 16B-unit XOR-by-(row&7) swizzle (conflict-free, absmax 0 in R5/R7/R8).
// q-stream fold retained from R8 (2 float4 per array per thread per tile).
__global__ __launch_bounds__(128, 2) void hinge_gemm(
    const unsigned char* __restrict__ A,    // pred_fp8 [BROWS][DDIM] row-major, 1024 B/row
    const unsigned char* __restrict__ Bm,   // gt_fp8
    const float* __restrict__ pos,          // [BROWS]
    const float4* __restrict__ qh,          // q_hat  as float4[2M]
    const float4* __restrict__ qr,          // q_real as float4[2M]
    float* __restrict__ out) {
    extern __shared__ unsigned char smem[];
    unsigned char* const As = smem;                     // [128][128] = 16 KB
    unsigned char* const Bs = smem + 16384;             // [128][128] = 16 KB
    float* const pos_s = (float*)(smem + 32768);        // 128 floats
    float* const sred  = (float*)(smem + 33280);        // 2 floats
    float* const sred2 = (float*)(smem + 33288);        // 2 floats

    // XCD map (grid 1024, 1024%8==0 -> round-robin orig%8 = XCD, bijective):
    // XCD k owns bm-strip [4k, 4k+4) x all bn. idx&3 cycles bm fastest so the 4 bm
    // sharing a bn run concurrently (B panel L2-reuse); A strip 512 rows stays resident.
    const int orig = blockIdx.x;
    const int xcd = orig & 7, idx = orig >> 3;    // idx 0..127
    const int bm = xcd * 4 + (idx & 3);           // 0..31
    const int bn = idx >> 2;                      // 0..31

    const int tid = threadIdx.x;
    const int lane = tid & 63;
    const int wave = tid >> 6;   // 0..1
    const int wn = wave;         // wave col: B rows wn*64 .. +63

    // staging geometry: chunk c (1 KB) = rows c*8..c*8+7 of a [128][128] tile.
    // wave w stages A chunks w*8..w*8+7 and B chunks w*8..w*8+7 (16 gload_lds/wave).
    // lane l -> row_in_chunk l>>3, fetches logical 16B unit (l&7)^(l>>3) so the tile
    // lands with phys_unit = log_unit ^ (row&7).
    const int grow = lane >> 3;
    const int usw  = (lane & 7) ^ grow;

    const unsigned char* Abase = A  + (size_t)(bm * 128) * DDIM;
    const unsigned char* Bbase = Bm + (size_t)(bn * 128) * DDIM;

    // q slice for this block: 2048 float4 per array
    const float4* qhb = qh + (size_t)orig * 2048;
    const float4* qrb = qr + (size_t)orig * 2048;

    f32x16 acc[4][2];
    #pragma unroll
    for (int i = 0; i < 4; i++)
        #pragma unroll
        for (int j = 0; j < 2; j++)
            #pragma unroll
            for (int r = 0; r < 16; r++) acc[i][j][r] = 0.0f;

    const int sc1 = 0x7f7f7f7f;        // E8M0 1.0 in every byte
    const int mrow = lane & 31;        // m (or n) within 32x32 tile
    const int kh = lane >> 5;          // 0..1: which 32-byte k-half of the mfma's K=64

    if (tid < 128) pos_s[tid] = pos[bm * 128 + tid];

    auto stage = [&](int k0) {
        #pragma unroll
        for (int i = 0; i < 8; i++) {
            const int c = wave * 8 + i;         // chunk 0..15
            const int row = c * 8 + grow;       // tile row 0..127
            __builtin_amdgcn_global_load_lds(
                (gu32*)(Abase + (size_t)row * DDIM + k0 + usw * 16),
                (su32*)(As + c * 1024), 16, 0, 0);
            __builtin_amdgcn_global_load_lds(
                (gu32*)(Bbase + (size_t)row * DDIM + k0 + usw * 16),
                (su32*)(Bs + c * 1024), 16, 0, 0);
        }
    };

    auto compute = [&]() {
        #pragma unroll
        for (int h = 0; h < 2; h++) {          // two K=64 mfma steps per staged BK=128
            const int u0 = h * 4 + kh * 2;     // logical 16B unit of this lane's k-block
            i32x8 af[4];
            i32x8 bg[2];
            #pragma unroll
            for (int mt = 0; mt < 4; mt++) {
                const int r = mt * 32 + mrow;
                i32x4 x0 = *(const i32x4*)&As[r * 128 + ((u0    ) ^ (r & 7)) * 16];
                i32x4 x1 = *(const i32x4*)&As[r * 128 + ((u0 + 1) ^ (r & 7)) * 16];
                af[mt] = __builtin_shufflevector(x0, x1, 0, 1, 2, 3, 4, 5, 6, 7);
            }
            #pragma unroll
            for (int nt = 0; nt < 2; nt++) {
                const int r = wn * 64 + nt * 32 + mrow;
                i32x4 x0 = *(const i32x4*)&Bs[r * 128 + ((u0    ) ^ (r & 7)) * 16];
                i32x4 x1 = *(const i32x4*)&Bs[r * 128 + ((u0 + 1) ^ (r & 7)) * 16];
                bg[nt] = __builtin_shufflevector(x0, x1, 0, 1, 2, 3, 4, 5, 6, 7);
            }
            __builtin_amdgcn_s_setprio(1);
            #pragma unroll
            for (int mt = 0; mt < 4; mt++)
                #pragma unroll
                for (int nt = 0; nt < 2; nt++)
                    acc[mt][nt] = __builtin_amdgcn_mfma_scale_f32_32x32x64_f8f6f4(
                        af[mt], bg[nt], acc[mt][nt], 0, 0, 0, sc1, 0, sc1);
            __builtin_amdgcn_s_setprio(0);
        }
    };

    // q-stream registers (named — rule #20)
    float ls = 0.0f;
    float4 ch0, ch1, cr0, cr1;   // current (landed at last tile's first barrier)
    float4 nh0, nh1, nr0, nr1;   // next (in flight)
    ch0 = qhb[tid];       ch1 = qhb[tid + 128];
    cr0 = qrb[tid];       cr1 = qrb[tid + 128];

    // R5-style loop: {stage + q-issue + q-accum} -> barrier (drains vmem+lgkm; hidden by
    // the 3 other blocks on this CU) -> compute -> barrier (WAR on single buffer).
    for (int t = 0; t < 8; t++) {
        stage(t * 128);
        if (t < 7) {
            const int qo = (t + 1) * 256 + tid;
            nh0 = qhb[qo];       nh1 = qhb[qo + 128];
            nr0 = qrb[qo];       nr1 = qrb[qo + 128];
        }
        ls += ch0.x * cr0.x + ch0.y * cr0.y + ch0.z * cr0.z + ch0.w * cr0.w
            + ch1.x * cr1.x + ch1.y * cr1.y + ch1.z * cr1.z + ch1.w * cr1.w;
        __syncthreads();
        compute();
        __syncthreads();
        ch0 = nh0; ch1 = nh1; cr0 = nr0; cr1 = nr1;
    }

    // epilogue: hinge + block reduction + local-loss fold
    // 32x32 C/D layout: col = lane&31 (gt idx), row = (reg&3) + 8*(reg>>2) + 4*(lane>>5)
    // (pred idx) [verified m74/m101; dtype-independent; R5/R7/R8 passed with absmax 0]
    float s = 0.0f;
    const int rq = 4 * kh;
    #pragma unroll
    for (int mt = 0; mt < 4; mt++) {
        #pragma unroll
        for (int nt = 0; nt < 2; nt++) {
            #pragma unroll
            for (int i = 0; i < 16; i++) {
                const int lr = mt * 32 + (i & 3) + 8 * (i >> 2) + rq;
                const float v = acc[mt][nt][i] - pos_s[lr] + 1.0f;
                s += fmaxf(v, 0.0f);
            }
        }
    }
    #pragma unroll
    for (int o = 32; o > 0; o >>= 1) {
        s  += __shfl_down(s, o, 64);
        ls += __shfl_down(ls, o, 64);
    }
    if (lane == 0) { sred[wave] = s; sred2[wave] = ls; }
    __syncthreads();
    if (tid == 0) {
        atomicAdd(out, sred[0] + sred[1]
                       - (sred2[0] + sred2[1]) * (1.0f / (float)LROWS));
    }
}

extern "C" void kernel_launch(void* const* d_in, const int* in_sizes, int n_in,
                              void* d_out, int out_size, void* d_ws, size_t ws_size,
                              hipStream_t stream) {
    const float* q_hat  = (const float*)d_in[0];
    const float* q_real = (const float*)d_in[1];
    const float* gt     = (const float*)d_in[2];  // encoded_gt
    const float* pred   = (const float*)d_in[3];  // encoded_pred
    float* out = (float*)d_out;

    // workspace layout: pred_fp8 (4MB) | gt_fp8 (4MB) | pos (16KB)
    char* ws = (char*)d_ws;
    unsigned char* pred_8 = (unsigned char*)ws;
    unsigned char* gt_8   = (unsigned char*)(ws + (size_t)BROWS * DDIM);
    float* pos   = (float*)(ws + (size_t)2 * BROWS * DDIM);

    hipLaunchKernelGGL(prep_kernel, dim3(BROWS), dim3(256), 0, stream,
                       (const float4*)pred, (const float4*)gt,
                       (unsigned int*)pred_8, (unsigned int*)gt_8,
                       pos, out);

    // 32 KB tile + 512 B pos + 16 B reduction scratch; 4 blocks/CU (131 KB of 160 KB)
    const size_t lds_bytes = 32768 + 512 + 16;
    hipLaunchKernelGGL(hinge_gemm, dim3(1024), dim3(128), lds_bytes, stream,
                       pred_8, gt_8, pos,
                       (const float4*)q_hat, (const float4*)q_real, out);
}

// Round 6
// 130.516 us; speedup vs baseline: 1.2070x; 1.2070x over previous
//
#include <hip/hip_runtime.h>
#include <hip/hip_bf16.h>

// Problem sizes (fixed by the reference)
#define LROWS 8192
#define BROWS 4096
#define DDIM  1024

typedef __attribute__((ext_vector_type(4)))  int   i32x4;
typedef __attribute__((ext_vector_type(8)))  int   i32x8;
typedef __attribute__((ext_vector_type(16))) float f32x16;

// address-space-qualified pointer typedefs for global_load_lds
typedef const unsigned int __attribute__((address_space(1))) gu32;
typedef unsigned int       __attribute__((address_space(3))) su32;

// pack 4 floats -> 4 fp8 e4m3 bytes (OCP e4m3fn on gfx950)
__device__ inline unsigned int pack_fp8x4(float4 v) {
    unsigned int w = 0;
    w = __builtin_amdgcn_cvt_pk_fp8_f32(v.x, v.y, w, false);  // bytes 0,1
    w = __builtin_amdgcn_cvt_pk_fp8_f32(v.z, v.w, w, true);   // bytes 2,3
    return w;
}

// ---------------- prep: fp32->fp8 cast + pos diag dots ONLY (unchanged from R8) ----------------
__global__ __launch_bounds__(256) void prep_kernel(
    const float4* __restrict__ pred,
    const float4* __restrict__ gt,
    unsigned int* __restrict__ opred,   // fp8, 256 uints per row
    unsigned int* __restrict__ ogt,
    float* __restrict__ pos,
    float* __restrict__ out) {
    __shared__ float sred[4];
    const int row = blockIdx.x;
    const int t = threadIdx.x;
    if (row == 0 && t == 0) out[0] = 0.0f;

    const int idx = row * 256 + t;
    float4 p = pred[idx];
    float4 g = gt[idx];
    opred[idx] = pack_fp8x4(p);
    ogt[idx]   = pack_fp8x4(g);
    float s = p.x * g.x + p.y * g.y + p.z * g.z + p.w * g.w;

    #pragma unroll
    for (int o = 32; o > 0; o >>= 1) s += __shfl_down(s, o, 64);
    if ((t & 63) == 0) sred[t >> 6] = s;
    __syncthreads();
    if (t == 0) pos[row] = sred[0] + sred[1] + sred[2] + sred[3];
}

// ---------------- hinge GEMM v7 (MX fp8): 256x256, faithful 2-phase-per-tile schedule ----------
// R12: R11 (2-wave small blocks) regressed hard — MfmaUtil 10%, Occupancy 18%: latency-
// starved, no cross-block antiphase. Reverted to the R8 geometry (256x256, 8 waves 2x4,
// wave 128x64 = 4x2 mfma_scale_32x32x64, BK=128 ping-pong, 1 block/CU) and applied the
// m201 phase recipe FAITHFULLY this time (R9's port had the m141 failure signature:
// sched_barrier(0) around everything + 4-MFMA micro-clusters + 8 barriers/tile):
//   phase h (h=0,1 per K-tile): {12 ds_read_b128 for h | 4 stage gload_lds}
//     -> raw s_barrier (read latency hides under barrier skew; NO counter drain)
//     -> setprio(1) + 8-MFMA cluster + setprio(0) -> raw s_barrier.
// Phase B extras: 4 q-loads issued after ONE sched_barrier(0) (pins stages before q so
// the FIFO count holds), and `s_waitcnt vmcnt(4)` after its MFMAs — ONE counted drain
// per K-tile (retires exactly the 8 stage ops, oldest in FIFO; q stays in flight).
// Hazards: RAW next-tile reads of p^1 gated by vmcnt(4)+barrier-2 (all waves) ✓; WAR
// stages into p^1 issue only after tile t-1's phase-B barrier-2, whose MFMAs consumed
// the last reads of p^1 ✓; barrier counts uniform over all 512 threads ✓; no in-loop
// ds_writes (pos_s covered in prologue) ✓. Compiler keeps scheduling freedom inside
// phases — plain-C++ ds_reads get fine-grained lgkmcnt automatically (m97).
__global__ __launch_bounds__(512, 2) void hinge_gemm(
    const unsigned char* __restrict__ A,    // pred_fp8 [BROWS][DDIM] row-major, 1024 B/row
    const unsigned char* __restrict__ Bm,   // gt_fp8
    const float* __restrict__ pos,          // [BROWS]
    const float4* __restrict__ qh,          // q_hat  as float4[2M]
    const float4* __restrict__ qr,          // q_real as float4[2M]
    float* __restrict__ out) {
    extern __shared__ unsigned char smem[];
    unsigned char* const As = smem;                       // [2][256*128] = 64 KB
    unsigned char* const Bs = smem + 65536;               // [2][256*128] = 64 KB
    float* const pos_s = (float*)(smem + 131072);         // 256 floats
    float* const sred  = (float*)(smem + 132096);         // 8 floats
    float* const sred2 = (float*)(smem + 132128);         // 8 floats

    // XCD-chunked swizzle: dispatch round-robins XCDs (orig % 8); XCD k owns a 4bm x 8bn
    // region (~3 MB L2 footprint).
    const int orig = blockIdx.x;
    const int xk = orig & 7, xj = orig >> 3;
    const int bm = (xk >> 1) * 4 + (xj >> 3);     // 0..15
    const int bn = (xk & 1) * 8 + (xj & 7);       // 0..15

    const int tid = threadIdx.x;
    const int lane = tid & 63;
    const int wave = tid >> 6;   // 0..7
    const int wm = wave >> 2;    // 0..1  wave row (128 rows each)
    const int wn = wave & 3;     // 0..3  wave col (64 cols each)

    // staging geometry: wave w owns chunks w*4..w*4+3 (A and B); chunk c = rows
    // c*8..c*8+7; lane l -> row_in_chunk l>>3, fetches logical 16B unit (l&7)^(l>>3)
    // so the tile lands with phys_unit = log_unit ^ (row&7).
    const int grow = lane >> 3;
    const int usw  = (lane & 7) ^ grow;

    const unsigned char* Abase = A  + (size_t)(bm * 256) * DDIM;
    const unsigned char* Bbase = Bm + (size_t)(bn * 256) * DDIM;

    // q slice for this block: 8192 float4 per array
    const float4* qhb = qh + (size_t)orig * 8192;
    const float4* qrb = qr + (size_t)orig * 8192;

    f32x16 acc[4][2];
    #pragma unroll
    for (int i = 0; i < 4; i++)
        #pragma unroll
        for (int j = 0; j < 2; j++)
            #pragma unroll
            for (int r = 0; r < 16; r++) acc[i][j][r] = 0.0f;

    const int sc1 = 0x7f7f7f7f;        // E8M0 1.0 in every byte
    const int mrow = lane & 31;        // m (or n) within 32x32 tile
    const int kh = lane >> 5;          // 0..1: which 32-byte k-half of the mfma's K=64

    // one chunk (A+B) of next-tile staging: 2 global_load_lds
    auto stage_one = [&](int buf, int k0, int i) {
        const int c = wave * 4 + i;
        const int row = c * 8 + grow;
        __builtin_amdgcn_global_load_lds(
            (gu32*)(Abase + (size_t)row * DDIM + k0 + usw * 16),
            (su32*)(As + buf * 32768 + c * 1024), 16, 0, 0);
        __builtin_amdgcn_global_load_lds(
            (gu32*)(Bbase + (size_t)row * DDIM + k0 + usw * 16),
            (su32*)(Bs + buf * 32768 + c * 1024), 16, 0, 0);
    };

    // full-tile compute, no barriers (final iteration only)
    auto compute = [&](int buf) {
        const unsigned char* Ab = As + buf * 32768;
        const unsigned char* Bb = Bs + buf * 32768;
        #pragma unroll
        for (int h = 0; h < 2; h++) {
            const int u0 = h * 4 + kh * 2;
            i32x8 af[4];
            i32x8 bg[2];
            #pragma unroll
            for (int mt = 0; mt < 4; mt++) {
                const int r = wm * 128 + mt * 32 + mrow;
                i32x4 x0 = *(const i32x4*)&Ab[r * 128 + ((u0    ) ^ (r & 7)) * 16];
                i32x4 x1 = *(const i32x4*)&Ab[r * 128 + ((u0 + 1) ^ (r & 7)) * 16];
                af[mt] = __builtin_shufflevector(x0, x1, 0, 1, 2, 3, 4, 5, 6, 7);
            }
            #pragma unroll
            for (int nt = 0; nt < 2; nt++) {
                const int r = wn * 64 + nt * 32 + mrow;
                i32x4 x0 = *(const i32x4*)&Bb[r * 128 + ((u0    ) ^ (r & 7)) * 16];
                i32x4 x1 = *(const i32x4*)&Bb[r * 128 + ((u0 + 1) ^ (r & 7)) * 16];
                bg[nt] = __builtin_shufflevector(x0, x1, 0, 1, 2, 3, 4, 5, 6, 7);
            }
            __builtin_amdgcn_s_setprio(1);
            #pragma unroll
            for (int mt = 0; mt < 4; mt++)
                #pragma unroll
                for (int nt = 0; nt < 2; nt++)
                    acc[mt][nt] = __builtin_amdgcn_mfma_scale_f32_32x32x64_f8f6f4(
                        af[mt], bg[nt], acc[mt][nt], 0, 0, 0, sc1, 0, sc1);
            __builtin_amdgcn_s_setprio(0);
        }
    };

    // q-stream registers (named — rule #20)
    float ls = 0.0f;
    float4 ch0, ch1, cr0, cr1;   // current (ready to accumulate)
    float4 nh0, nh1, nr0, nr1;   // next (in flight)

    // prologue: pos stage + tile-0 stage (8 vmem) + q chunk 0 (4 vmem);
    // vmcnt(4) retires the stages, keeps q in flight; lgkmcnt(0) covers pos_s write.
    if (tid < 256) pos_s[tid] = pos[bm * 256 + tid];
    #pragma unroll
    for (int i = 0; i < 4; i++) stage_one(0, 0, i);
    __builtin_amdgcn_sched_barrier(0);          // stages strictly before q-loads (FIFO count)
    ch0 = qhb[tid];       ch1 = qhb[tid + 512];
    cr0 = qrb[tid];       cr1 = qrb[tid + 512];
    asm volatile("s_waitcnt vmcnt(4) lgkmcnt(0)" ::: "memory");
    __builtin_amdgcn_s_barrier();

    int p = 0;
    for (int t = 0; t < 7; ++t) {
        const int k0n = (t + 1) * 128;
        const unsigned char* Ab = As + p * 32768;
        const unsigned char* Bb = Bs + p * 32768;
        #pragma unroll
        for (int h = 0; h < 2; ++h) {
            const int u0 = h * 4 + kh * 2;
            // --- phase front: 12 ds_read_b128 for this phase + 4 stage issues ---
            i32x8 af0, af1, af2, af3, bg0, bg1;
            {
                const int r = wm * 128 + 0 * 32 + mrow;
                i32x4 x0 = *(const i32x4*)&Ab[r * 128 + ((u0    ) ^ (r & 7)) * 16];
                i32x4 x1 = *(const i32x4*)&Ab[r * 128 + ((u0 + 1) ^ (r & 7)) * 16];
                af0 = __builtin_shufflevector(x0, x1, 0, 1, 2, 3, 4, 5, 6, 7);
            }
            {
                const int r = wm * 128 + 1 * 32 + mrow;
                i32x4 x0 = *(const i32x4*)&Ab[r * 128 + ((u0    ) ^ (r & 7)) * 16];
                i32x4 x1 = *(const i32x4*)&Ab[r * 128 + ((u0 + 1) ^ (r & 7)) * 16];
                af1 = __builtin_shufflevector(x0, x1, 0, 1, 2, 3, 4, 5, 6, 7);
            }
            {
                const int r = wm * 128 + 2 * 32 + mrow;
                i32x4 x0 = *(const i32x4*)&Ab[r * 128 + ((u0    ) ^ (r & 7)) * 16];
                i32x4 x1 = *(const i32x4*)&Ab[r * 128 + ((u0 + 1) ^ (r & 7)) * 16];
                af2 = __builtin_shufflevector(x0, x1, 0, 1, 2, 3, 4, 5, 6, 7);
            }
            {
                const int r = wm * 128 + 3 * 32 + mrow;
                i32x4 x0 = *(const i32x4*)&Ab[r * 128 + ((u0    ) ^ (r & 7)) * 16];
                i32x4 x1 = *(const i32x4*)&Ab[r * 128 + ((u0 + 1) ^ (r & 7)) * 16];
                af3 = __builtin_shufflevector(x0, x1, 0, 1, 2, 3, 4, 5, 6, 7);
            }
            {
                const int r = wn * 64 + 0 * 32 + mrow;
                i32x4 x0 = *(const i32x4*)&Bb[r * 128 + ((u0    ) ^ (r & 7)) * 16];
                i32x4 x1 = *(const i32x4*)&Bb[r * 128 + ((u0 + 1) ^ (r & 7)) * 16];
                bg0 = __builtin_shufflevector(x0, x1, 0, 1, 2, 3, 4, 5, 6, 7);
            }
            {
                const int r = wn * 64 + 1 * 32 + mrow;
                i32x4 x0 = *(const i32x4*)&Bb[r * 128 + ((u0    ) ^ (r & 7)) * 16];
                i32x4 x1 = *(const i32x4*)&Bb[r * 128 + ((u0 + 1) ^ (r & 7)) * 16];
                bg1 = __builtin_shufflevector(x0, x1, 0, 1, 2, 3, 4, 5, 6, 7);
            }
            // 4 stage issues for next tile (phase A: chunks 0,1; phase B: chunks 2,3)
            stage_one(p ^ 1, k0n, h * 2);
            stage_one(p ^ 1, k0n, h * 2 + 1);
            if (h == 1) {
                // pin: all 8 stages precede the q-loads so vmcnt(4) counts exactly q
                __builtin_amdgcn_sched_barrier(0);
                const int qo = (t + 1) * 1024 + tid;
                nh0 = qhb[qo];       nh1 = qhb[qo + 512];
                nr0 = qrb[qo];       nr1 = qrb[qo + 512];
                ls += ch0.x * cr0.x + ch0.y * cr0.y + ch0.z * cr0.z + ch0.w * cr0.w
                    + ch1.x * cr1.x + ch1.y * cr1.y + ch1.z * cr1.z + ch1.w * cr1.w;
            }
            // --- barrier 1: read latency hides under barrier skew (raw, no drain) ---
            __builtin_amdgcn_s_barrier();
            // --- MFMA cluster (compiler-inserted lgkmcnt gates on the ds_reads) ---
            __builtin_amdgcn_s_setprio(1);
            acc[0][0] = __builtin_amdgcn_mfma_scale_f32_32x32x64_f8f6f4(af0, bg0, acc[0][0], 0, 0, 0, sc1, 0, sc1);
            acc[0][1] = __builtin_amdgcn_mfma_scale_f32_32x32x64_f8f6f4(af0, bg1, acc[0][1], 0, 0, 0, sc1, 0, sc1);
            acc[1][0] = __builtin_amdgcn_mfma_scale_f32_32x32x64_f8f6f4(af1, bg0, acc[1][0], 0, 0, 0, sc1, 0, sc1);
            acc[1][1] = __builtin_amdgcn_mfma_scale_f32_32x32x64_f8f6f4(af1, bg1, acc[1][1], 0, 0, 0, sc1, 0, sc1);
            acc[2][0] = __builtin_amdgcn_mfma_scale_f32_32x32x64_f8f6f4(af2, bg0, acc[2][0], 0, 0, 0, sc1, 0, sc1);
            acc[2][1] = __builtin_amdgcn_mfma_scale_f32_32x32x64_f8f6f4(af2, bg1, acc[2][1], 0, 0, 0, sc1, 0, sc1);
            acc[3][0] = __builtin_amdgcn_mfma_scale_f32_32x32x64_f8f6f4(af3, bg0, acc[3][0], 0, 0, 0, sc1, 0, sc1);
            acc[3][1] = __builtin_amdgcn_mfma_scale_f32_32x32x64_f8f6f4(af3, bg1, acc[3][1], 0, 0, 0, sc1, 0, sc1);
            __builtin_amdgcn_s_setprio(0);
            if (h == 1) {
                // one counted drain per K-tile: retire the 8 stage ops, keep q in flight
                asm volatile("s_waitcnt vmcnt(4)" ::: "memory");
            }
            // --- barrier 2: phase rhythm + (at h==1) next-tile RAW gate ---
            __builtin_amdgcn_s_barrier();
        }
        ch0 = nh0; ch1 = nh1; cr0 = nr0; cr1 = nr1;
        p ^= 1;
    }
    ls += ch0.x * cr0.x + ch0.y * cr0.y + ch0.z * cr0.z + ch0.w * cr0.w
        + ch1.x * cr1.x + ch1.y * cr1.y + ch1.z * cr1.z + ch1.w * cr1.w;
    compute(p);   // last tile: staged + drained + barrier'd at t=6

    // epilogue: hinge + block reduction + local-loss fold
    // 32x32 C/D layout: col = lane&31 (gt idx), row = (reg&3) + 8*(reg>>2) + 4*(lane>>5)
    // (pred idx) [verified m74/m101; dtype-independent; R5/R7/R8 passed with absmax 0]
    float s = 0.0f;
    const int rq = 4 * kh;
    #pragma unroll
    for (int mt = 0; mt < 4; mt++) {
        #pragma unroll
        for (int nt = 0; nt < 2; nt++) {
            #pragma unroll
            for (int i = 0; i < 16; i++) {
                const int lr = wm * 128 + mt * 32 + (i & 3) + 8 * (i >> 2) + rq;
                const float v = acc[mt][nt][i] - pos_s[lr] + 1.0f;
                s += fmaxf(v, 0.0f);
            }
        }
    }
    #pragma unroll
    for (int o = 32; o > 0; o >>= 1) {
        s  += __shfl_down(s, o, 64);
        ls += __shfl_down(ls, o, 64);
    }
    if (lane == 0) { sred[wave] = s; sred2[wave] = ls; }
    __syncthreads();
    if (tid == 0) {
        float tot = 0.0f, lp = 0.0f;
        #pragma unroll
        for (int w = 0; w < 8; w++) { tot += sred[w]; lp += sred2[w]; }
        atomicAdd(out, tot - lp * (1.0f / (float)LROWS));
    }
}

extern "C" void kernel_launch(void* const* d_in, const int* in_sizes, int n_in,
                              void* d_out, int out_size, void* d_ws, size_t ws_size,
                              hipStream_t stream) {
    const float* q_hat  = (const float*)d_in[0];
    const float* q_real = (const float*)d_in[1];
    const float* gt     = (const float*)d_in[2];  // encoded_gt
    const float* pred   = (const float*)d_in[3];  // encoded_pred
    float* out = (float*)d_out;

    // workspace layout: pred_fp8 (4MB) | gt_fp8 (4MB) | pos (16KB)
    char* ws = (char*)d_ws;
    unsigned char* pred_8 = (unsigned char*)ws;
    unsigned char* gt_8   = (unsigned char*)(ws + (size_t)BROWS * DDIM);
    float* pos   = (float*)(ws + (size_t)2 * BROWS * DDIM);

    hipLaunchKernelGGL(prep_kernel, dim3(BROWS), dim3(256), 0, stream,
                       (const float4*)pred, (const float4*)gt,
                       (unsigned int*)pred_8, (unsigned int*)gt_8,
                       pos, out);

    // 128 KB tiles + 1 KB pos + 2x32 B reduction scratch of dynamic LDS (1 block/CU)
    const size_t lds_bytes = 131072 + 1024 + 64;
    hipLaunchKernelGGL(hinge_gemm, dim3(256), dim3(512), lds_bytes, stream,
                       pred_8, gt_8, pos,
                       (const float4*)q_hat, (const float4*)q_real, out);
}